// Round 4
// baseline (62.318 us; speedup 1.0000x reference)
//
#include <hip/hip_runtime.h>

#define LL 197
#define NN 128
#define DD 768
#define TT 16
#define PP 196
#define NSLICE 49                 // p-slices per b, 4 p each
#define SCL 0.03608439182435161f  // 1/sqrt(768)

typedef short short8 __attribute__((ext_vector_type(8)));
typedef float f32x4 __attribute__((ext_vector_type(4)));

static __device__ __forceinline__ ushort f2bf(float f) {
    union { float f; unsigned int u; } a; a.f = f;
    unsigned int r = a.u + 0x7fffu + ((a.u >> 16) & 1u);
    return (ushort)(r >> 16);
}

// Swizzled LDS index for the 32x768 bf16 V tile: 16B-block XOR on row low bits.
static __device__ __forceinline__ int vidx(int r, int d) {
    return r * DD + ((((d >> 3) ^ (r & 7)) << 3) | (d & 7));
}

// ---------------- K1: LayerNorm fp32 -> bf16, one wave per row ----------------
__global__ __launch_bounds__(256) void k_ln(const float* __restrict__ x,
                                            const float* __restrict__ gamma,
                                            const float* __restrict__ beta,
                                            ushort* __restrict__ xn) {
    int row  = (blockIdx.x << 2) + (threadIdx.x >> 6);
    int lane = threadIdx.x & 63;
    const float4* xr = (const float4*)(x + (size_t)row * DD);
    float4 v[3];
    float s = 0.f, ss = 0.f;
#pragma unroll
    for (int j = 0; j < 3; ++j) {
        v[j] = xr[lane + 64 * j];
        s  += v[j].x + v[j].y + v[j].z + v[j].w;
        ss = fmaf(v[j].x, v[j].x, ss); ss = fmaf(v[j].y, v[j].y, ss);
        ss = fmaf(v[j].z, v[j].z, ss); ss = fmaf(v[j].w, v[j].w, ss);
    }
#pragma unroll
    for (int o = 32; o > 0; o >>= 1) { s += __shfl_xor(s, o); ss += __shfl_xor(ss, o); }
    float mu  = s * (1.f / DD);
    float var = fmaf(ss, 1.f / DD, -mu * mu);
    float rs  = rsqrtf(var + 1e-5f);
    const float4* g4 = (const float4*)gamma;
    const float4* b4 = (const float4*)beta;
    ushort4* outr = (ushort4*)(xn + (size_t)row * DD);
#pragma unroll
    for (int j = 0; j < 3; ++j) {
        int i4 = lane + 64 * j;
        float4 g = g4[i4], b = b4[i4];
        ushort4 o4;
        o4.x = f2bf((v[j].x - mu) * rs * g.x + b.x);
        o4.y = f2bf((v[j].y - mu) * rs * g.y + b.y);
        o4.z = f2bf((v[j].z - mu) * rs * g.z + b.z);
        o4.w = f2bf((v[j].w - mu) * rs * g.w + b.w);
        outr[i4] = o4;
    }
}

// ---------------- K2: banded attention via MFMA (safe-primitive version) -----
// Block = (b, slice of 4 p). Per 32-row tile (2 p x 16 m):
//   stage V rows into LDS (reg-staged ds_write_b128, swizzled row-major),
//   mm1: S[16t x 32r] = Q . V^T (K=768 split over wave pairs, combine in LDS),
//   W = sigmoid(S*scl)-0.5 masked to band |m-t|<=2, packed in A-frag order,
//   mm2: feat[16t x 768d] += W . V (B-frags via 8x ds_read_u16 gather).
template<bool USE_PART>
__global__ __launch_bounds__(256, 3) void k_attn(const ushort* __restrict__ xn,
                                                 float* __restrict__ outp) {
    __shared__ ushort Vl[32 * DD];     // 49152 B
    __shared__ float  Sl[2][TT][32];   // 4096 B
    __shared__ ushort Wl[TT * 32];     // 1024 B, A-frag order

    int gid = blockIdx.x;
    int b = gid / NSLICE, sl = gid % NSLICE;
    int w   = threadIdx.x >> 6, l = threadIdx.x & 63;
    int wq  = w & 1, kh = w >> 1;
    int l15 = l & 15, lh = l >> 4;

    const ushort* qbase = xn + (size_t)(b * TT + l15) * DD;  // LN'd cls row l15

    f32x4 acc[12];
#pragma unroll
    for (int i = 0; i < 12; ++i) acc[i] = (f32x4){0.f, 0.f, 0.f, 0.f};

    for (int tp = 0; tp < 2; ++tp) {
        int p0 = sl * 4 + tp * 2;

        // ---- stage: 32 rows x 768 elems, 8-elem blocks, 12 per thread ----
#pragma unroll
        for (int cc = 0; cc < 12; ++cc) {
            int e  = cc * 256 + threadIdx.x;   // 0..3071
            int r  = e / 96;
            int c8 = e - r * 96;
            const ushort* src =
                xn + ((size_t)(1 + p0 + (r >> 4)) * NN + b * TT + (r & 15)) * DD + c8 * 8;
            *(short8*)&Vl[vidx(r, c8 * 8)] = *(const short8*)src;
        }
        __syncthreads();

        // ---- mm1: partial S over this wave's k-half ----
        f32x4 sacc = (f32x4){0.f, 0.f, 0.f, 0.f};
        int vr = wq * 16 + l15;                // tile row this lane serves as B-col
#pragma unroll
        for (int s = 0; s < 12; ++s) {
            int k0 = kh * 384 + s * 32 + lh * 8;
            short8 afr = *(const short8*)(qbase + k0);
            short8 bfr = *(const short8*)&Vl[vidx(vr, k0)];
            sacc = __builtin_amdgcn_mfma_f32_16x16x32_bf16(afr, bfr, sacc, 0, 0, 0);
        }
#pragma unroll
        for (int q = 0; q < 4; ++q) Sl[kh][lh * 4 + q][wq * 16 + l15] = sacc[q];
        __syncthreads();

        // ---- W = band-masked sigmoid(S)-0.5, packed in A-frag order ----
        {
            int t  = threadIdx.x & 15;
            int r  = (threadIdx.x >> 4) * 2;   // even r, pair (r, r+1)
            float s0 = Sl[0][t][r]     + Sl[1][t][r];
            float s1 = Sl[0][t][r + 1] + Sl[1][t][r + 1];
            int m0 = r & 15, m1 = (r + 1) & 15;
            float w0 = (m0 - t <= 2 && t - m0 <= 2)
                         ? (1.f / (1.f + __expf(-s0 * SCL)) - 0.5f) : 0.f;
            float w1 = (m1 - t <= 2 && t - m1 <= 2)
                         ? (1.f / (1.f + __expf(-s1 * SCL)) - 0.5f) : 0.f;
            unsigned pk = (unsigned)f2bf(w0) | ((unsigned)f2bf(w1) << 16);
            *(unsigned*)((char*)Wl + (t + (r >> 3) * 16) * 16 + (r & 7) * 2) = pk;
        }
        __syncthreads();

        // ---- mm2: feat += W . V (wave owns d-slice [w*192, w*192+192)) ----
        short8 wfrag = *(const short8*)((const char*)Wl + l * 16);
#pragma unroll
        for (int i = 0; i < 12; ++i) {
            int d0 = w * 192 + i * 16;
            union { ushort s[8]; short8 v; } u;
#pragma unroll
            for (int j = 0; j < 8; ++j)
                u.s[j] = Vl[vidx(lh * 8 + j, d0 + l15)];
            acc[i] = __builtin_amdgcn_mfma_f32_16x16x32_bf16(wfrag, u.v, acc[i], 0, 0, 0);
        }
        __syncthreads();   // protect Vl before next tile's stage
    }

    // ---- epilogue: C/D layout col=l&15, row=(l>>4)*4+q ----
#pragma unroll
    for (int i = 0; i < 12; ++i) {
        int d = w * 192 + i * 16 + l15;
#pragma unroll
        for (int q = 0; q < 4; ++q) {
            int t = lh * 4 + q;
            if (USE_PART) {
                outp[((size_t)(sl * 8 + b) * TT + t) * DD + d] = acc[i][q];
            } else {
                atomicAdd(outp + (size_t)(b * TT + t) * DD + d, acc[i][q]);
            }
        }
    }
}

// ---------------- K3: reduce 49 slice-partials ----------------
__global__ __launch_bounds__(256) void k_reduce(const float* __restrict__ part,
                                                float* __restrict__ out) {
    int e = blockIdx.x * 256 + threadIdx.x;    // float4 index over 24576
    const float4* p4 = (const float4*)part;
    float4 s = {0.f, 0.f, 0.f, 0.f};
#pragma unroll 7
    for (int sl = 0; sl < NSLICE; ++sl) {
        float4 v = p4[(size_t)sl * 24576 + e];
        s.x += v.x; s.y += v.y; s.z += v.z; s.w += v.w;
    }
    ((float4*)out)[e] = s;
}

extern "C" void kernel_launch(void* const* d_in, const int* in_sizes, int n_in,
                              void* d_out, int out_size, void* d_ws, size_t ws_size,
                              hipStream_t stream) {
    const float* x     = (const float*)d_in[0];
    const float* gamma = (const float*)d_in[1];
    const float* beta  = (const float*)d_in[2];
    float* out = (float*)d_out;

    const size_t xn_bytes   = (size_t)LL * NN * DD * 2;            // 38,731,776
    const size_t part_bytes = (size_t)NSLICE * 8 * TT * DD * 4;    // 19,267,584
    ushort* xn  = (ushort*)d_ws;
    float* part = (float*)((char*)d_ws + xn_bytes);
    bool use_part = ws_size >= xn_bytes + part_bytes;

    hipMemsetAsync(d_out, 0, (size_t)NN * DD * sizeof(float), stream);
    k_ln<<<(LL * NN) / 4, 256, 0, stream>>>(x, gamma, beta, xn);
    if (use_part) {
        k_attn<true><<<8 * NSLICE, 256, 0, stream>>>(xn, part);
        k_reduce<<<96, 256, 0, stream>>>(part, out);
    } else {
        k_attn<false><<<8 * NSLICE, 256, 0, stream>>>(xn, out);
    }
}

// Round 5
// 44.628 us; speedup vs baseline: 1.3964x; 1.3964x over previous
//
#include <hip/hip_runtime.h>

#define LL 197
#define NN 128
#define DD 768
#define TT 16
#define PP 196
#define NSLICE 49                 // p-slices per b, 4 p each
#define SCL 0.03608439182435161f  // 1/sqrt(768)

typedef short short8 __attribute__((ext_vector_type(8)));
typedef float f32x4 __attribute__((ext_vector_type(4)));

static __device__ __forceinline__ ushort f2bf(float f) {
    union { float f; unsigned int u; } a; a.f = f;
    unsigned int r = a.u + 0x7fffu + ((a.u >> 16) & 1u);
    return (ushort)(r >> 16);
}

// Swizzled LDS index for the 32x768 bf16 V tile: 16B-block XOR on row low bits.
static __device__ __forceinline__ int vidx(int r, int d) {
    return r * DD + ((((d >> 3) ^ (r & 7)) << 3) | (d & 7));
}

// ---------------- K1: LayerNorm fp32 -> bf16, one wave per row ----------------
__global__ __launch_bounds__(256) void k_ln(const float* __restrict__ x,
                                            const float* __restrict__ gamma,
                                            const float* __restrict__ beta,
                                            ushort* __restrict__ xn) {
    int row  = (blockIdx.x << 2) + (threadIdx.x >> 6);
    int lane = threadIdx.x & 63;
    const float4* xr = (const float4*)(x + (size_t)row * DD);
    float4 v[3];
    float s = 0.f, ss = 0.f;
#pragma unroll
    for (int j = 0; j < 3; ++j) {
        v[j] = xr[lane + 64 * j];
        s  += v[j].x + v[j].y + v[j].z + v[j].w;
        ss = fmaf(v[j].x, v[j].x, ss); ss = fmaf(v[j].y, v[j].y, ss);
        ss = fmaf(v[j].z, v[j].z, ss); ss = fmaf(v[j].w, v[j].w, ss);
    }
#pragma unroll
    for (int o = 32; o > 0; o >>= 1) { s += __shfl_xor(s, o); ss += __shfl_xor(ss, o); }
    float mu  = s * (1.f / DD);
    float var = fmaf(ss, 1.f / DD, -mu * mu);
    float rs  = rsqrtf(var + 1e-5f);
    const float4* g4 = (const float4*)gamma;
    const float4* b4 = (const float4*)beta;
    ushort4* outr = (ushort4*)(xn + (size_t)row * DD);
#pragma unroll
    for (int j = 0; j < 3; ++j) {
        int i4 = lane + 64 * j;
        float4 g = g4[i4], b = b4[i4];
        ushort4 o4;
        o4.x = f2bf((v[j].x - mu) * rs * g.x + b.x);
        o4.y = f2bf((v[j].y - mu) * rs * g.y + b.y);
        o4.z = f2bf((v[j].z - mu) * rs * g.z + b.z);
        o4.w = f2bf((v[j].w - mu) * rs * g.w + b.w);
        outr[i4] = o4;
    }
}

// ---------------- K2: banded attention via MFMA, tile-1 register prefetch ----
template<bool USE_PART>
__global__ __launch_bounds__(256, 3) void k_attn(const ushort* __restrict__ xn,
                                                 float* __restrict__ outp) {
    __shared__ ushort Vl[32 * DD];     // 49152 B
    __shared__ float  Sl[2][TT][32];   // 4096 B
    __shared__ ushort Wl[TT * 32];     // 1024 B, A-frag order

    int gid = blockIdx.x;
    int b = gid / NSLICE, sl = gid % NSLICE;
    int w   = threadIdx.x >> 6, l = threadIdx.x & 63;
    int wq  = w & 1, kh = w >> 1;
    int l15 = l & 15, lh = l >> 4;

    const ushort* qbase = xn + (size_t)(b * TT + l15) * DD;  // LN'd cls row l15

    f32x4 acc[12];
#pragma unroll
    for (int i = 0; i < 12; ++i) acc[i] = (f32x4){0.f, 0.f, 0.f, 0.f};

    int p0 = sl * 4;
    short8 stg[12];

#define LOADV(POFF)                                                              \
    _Pragma("unroll")                                                            \
    for (int cc = 0; cc < 12; ++cc) {                                            \
        int e  = cc * 256 + threadIdx.x;                                         \
        int r  = e / 96;                                                         \
        int c8 = e - r * 96;                                                     \
        stg[cc] = *(const short8*)(xn +                                          \
            ((size_t)(1 + p0 + (POFF) + (r >> 4)) * NN + b * TT + (r & 15)) * DD \
            + c8 * 8);                                                           \
    }

#define WRITEV()                                                                 \
    _Pragma("unroll")                                                            \
    for (int cc = 0; cc < 12; ++cc) {                                            \
        int e  = cc * 256 + threadIdx.x;                                         \
        int r  = e / 96;                                                         \
        int c8 = e - r * 96;                                                     \
        *(short8*)&Vl[vidx(r, c8 * 8)] = stg[cc];                                \
    }

#define COMPUTE()                                                                \
    {                                                                            \
        f32x4 sacc = (f32x4){0.f, 0.f, 0.f, 0.f};                                \
        int vr = wq * 16 + l15;                                                  \
        _Pragma("unroll")                                                        \
        for (int s = 0; s < 12; ++s) {                                           \
            int k0 = kh * 384 + s * 32 + lh * 8;                                 \
            short8 afr = *(const short8*)(qbase + k0);                           \
            short8 bfr = *(const short8*)&Vl[vidx(vr, k0)];                      \
            sacc = __builtin_amdgcn_mfma_f32_16x16x32_bf16(afr, bfr, sacc, 0, 0, 0); \
        }                                                                        \
        _Pragma("unroll")                                                        \
        for (int q = 0; q < 4; ++q) Sl[kh][lh * 4 + q][wq * 16 + l15] = sacc[q]; \
        __syncthreads();                                                         \
        {                                                                        \
            int t = threadIdx.x & 15;                                            \
            int r = (threadIdx.x >> 4) * 2;                                      \
            float s0 = Sl[0][t][r]     + Sl[1][t][r];                            \
            float s1 = Sl[0][t][r + 1] + Sl[1][t][r + 1];                        \
            int m0 = r & 15, m1 = (r + 1) & 15;                                  \
            float w0 = (m0 - t <= 2 && t - m0 <= 2)                              \
                         ? (1.f / (1.f + __expf(-s0 * SCL)) - 0.5f) : 0.f;       \
            float w1 = (m1 - t <= 2 && t - m1 <= 2)                              \
                         ? (1.f / (1.f + __expf(-s1 * SCL)) - 0.5f) : 0.f;       \
            unsigned pk = (unsigned)f2bf(w0) | ((unsigned)f2bf(w1) << 16);       \
            *(unsigned*)((char*)Wl + (t + (r >> 3) * 16) * 16 + (r & 7) * 2) = pk; \
        }                                                                        \
        __syncthreads();                                                         \
        short8 wfrag = *(const short8*)((const char*)Wl + l * 16);               \
        _Pragma("unroll")                                                        \
        for (int i = 0; i < 12; ++i) {                                           \
            int d0 = w * 192 + i * 16;                                           \
            union { ushort sv[8]; short8 v; } u;                                 \
            _Pragma("unroll")                                                    \
            for (int j = 0; j < 8; ++j)                                          \
                u.sv[j] = Vl[vidx(lh * 8 + j, d0 + l15)];                        \
            acc[i] = __builtin_amdgcn_mfma_f32_16x16x32_bf16(wfrag, u.v, acc[i], 0, 0, 0); \
        }                                                                        \
    }

    // tile 0: load + write LDS
    LOADV(0);
    WRITEV();
    __syncthreads();
    // prefetch tile 1 into registers (in flight during tile-0 compute)
    LOADV(2);
    COMPUTE();          // tile 0
    __syncthreads();    // Vl last use done
    WRITEV();           // tile 1 (compiler inserts vmcnt wait on stg)
    __syncthreads();
    COMPUTE();          // tile 1

#undef LOADV
#undef WRITEV
#undef COMPUTE

    // ---- epilogue: C/D layout col=l&15, row=(l>>4)*4+q ----
#pragma unroll
    for (int i = 0; i < 12; ++i) {
        int d = w * 192 + i * 16 + l15;
#pragma unroll
        for (int q = 0; q < 4; ++q) {
            int t = lh * 4 + q;
            if (USE_PART) {
                outp[((size_t)(sl * 8 + b) * TT + t) * DD + d] = acc[i][q];
            } else {
                atomicAdd(outp + (size_t)(b * TT + t) * DD + d, acc[i][q]);
            }
        }
    }
}

// ---------------- K3: reduce 49 slice-partials ----------------
__global__ __launch_bounds__(256) void k_reduce(const float* __restrict__ part,
                                                float* __restrict__ out) {
    int e = blockIdx.x * 256 + threadIdx.x;    // float4 index over 24576
    const float4* p4 = (const float4*)part;
    float4 s = {0.f, 0.f, 0.f, 0.f};
#pragma unroll 7
    for (int sl = 0; sl < NSLICE; ++sl) {
        float4 v = p4[(size_t)sl * 24576 + e];
        s.x += v.x; s.y += v.y; s.z += v.z; s.w += v.w;
    }
    ((float4*)out)[e] = s;
}

__global__ __launch_bounds__(256) void k_zero(float* __restrict__ out) {
    out[blockIdx.x * 256 + threadIdx.x] = 0.f;
}

extern "C" void kernel_launch(void* const* d_in, const int* in_sizes, int n_in,
                              void* d_out, int out_size, void* d_ws, size_t ws_size,
                              hipStream_t stream) {
    const float* x     = (const float*)d_in[0];
    const float* gamma = (const float*)d_in[1];
    const float* beta  = (const float*)d_in[2];
    float* out = (float*)d_out;

    const size_t xn_bytes   = (size_t)LL * NN * DD * 2;            // 38,731,776
    const size_t part_bytes = (size_t)NSLICE * 8 * TT * DD * 4;    // 19,267,584
    ushort* xn  = (ushort*)d_ws;
    float* part = (float*)((char*)d_ws + xn_bytes);
    bool use_part = ws_size >= xn_bytes + part_bytes;

    k_ln<<<(LL * NN) / 4, 256, 0, stream>>>(x, gamma, beta, xn);
    if (use_part) {
        k_attn<true><<<8 * NSLICE, 256, 0, stream>>>(xn, part);
        k_reduce<<<96, 256, 0, stream>>>(part, out);
    } else {
        k_zero<<<NN * DD / 256, 256, 0, stream>>>(out);
        k_attn<false><<<8 * NSLICE, 256, 0, stream>>>(xn, out);
    }
}